// Round 5
// baseline (502.541 us; speedup 1.0000x reference)
//
#include <hip/hip_runtime.h>
#include <math.h>

#define NUM_EMB 512
#define EDIM 64
#define BATCH 32
#define HW 4096
#define NROWS (BATCH * HW)        // 131072
#define NQ (NROWS * EDIM)         // 8388608
#define XSTRIDE 68                // 64 + 4 pad: keeps ds_read_b128 16B-aligned,
                                  // bank-start 4*(rl+m)%32 -> conflict-free b128

// numpy pairwise_sum for n=64 contiguous fp32 (tiny prep kernel only).
__device__ __forceinline__ float pairwise8_64(const float* v) {
    float r0 = v[0], r1 = v[1], r2 = v[2], r3 = v[3];
    float r4 = v[4], r5 = v[5], r6 = v[6], r7 = v[7];
#pragma unroll
    for (int i = 8; i < 64; i += 8) {
        r0 = __fadd_rn(r0, v[i + 0]);
        r1 = __fadd_rn(r1, v[i + 1]);
        r2 = __fadd_rn(r2, v[i + 2]);
        r3 = __fadd_rn(r3, v[i + 3]);
        r4 = __fadd_rn(r4, v[i + 4]);
        r5 = __fadd_rn(r5, v[i + 5]);
        r6 = __fadd_rn(r6, v[i + 6]);
        r7 = __fadd_rn(r7, v[i + 7]);
    }
    return __fadd_rn(__fadd_rn(__fadd_rn(r0, r1), __fadd_rn(r2, r3)),
                     __fadd_rn(__fadd_rn(r4, r5), __fadd_rn(r6, r7)));
}

// ws_f layout: [0] = loss sum accumulator, [8..8+511] = t2[k] = ||emb_k||^2
__global__ void vq_prep(const float* __restrict__ emb, float* __restrict__ ws_f) {
    int k = blockIdx.x * blockDim.x + threadIdx.x;
    if (k == 0) ws_f[0] = 0.0f;
    if (k < NUM_EMB) {
        const float* e = emb + k * EDIM;
        float sq[EDIM];
#pragma unroll
        for (int c = 0; c < EDIM; ++c) sq[c] = __fmul_rn(e[c], e[c]);
        ws_f[8 + k] = pairwise8_64(sq);
    }
}

__global__ __launch_bounds__(512, 4) void vq_main(const float* __restrict__ z,
                                                  const float* __restrict__ emb,
                                                  float* __restrict__ out,
                                                  float* __restrict__ ws_f) {
    __shared__ float xs[256 * XSTRIDE];   // 69632 B: x-tile, padded
    __shared__ float cb[512];             // combine: best dist
    __shared__ int   ck[512];             // combine: best k

    const int tid  = threadIdx.x;
    const int rl   = tid & 255;           // local row 0..255
    const int half = tid >> 8;            // k-half: 0 -> k<256, 1 -> k>=256
    const int r    = blockIdx.x * 256 + rl;
    const int b    = r >> 12;
    const int hw   = r & 4095;

    // ---- stage x-tile: each thread writes 8 float4 of its row's c-half ----
    const float* zb = z + (size_t)b * (EDIM * HW) + hw;
#pragma unroll
    for (int j = 0; j < 8; ++j) {
        const int c0 = half * 32 + j * 4;
        float4 v;
        v.x = zb[(size_t)(c0 + 0) * HW];   // coalesced: lanes -> consecutive hw
        v.y = zb[(size_t)(c0 + 1) * HW];
        v.z = zb[(size_t)(c0 + 2) * HW];
        v.w = zb[(size_t)(c0 + 3) * HW];
        *(float4*)&xs[rl * XSTRIDE + c0] = v;
    }
    __syncthreads();

    const float* xrow = &xs[rl * XSTRIDE];

    // ---- t1 = ||x||^2 in exact numpy pairwise-8 order, streamed from LDS ----
    float p0, p1, p2, p3, p4, p5, p6, p7;
    {
        float4 v = *(const float4*)&xrow[0];
        p0 = __fmul_rn(v.x, v.x); p1 = __fmul_rn(v.y, v.y);
        p2 = __fmul_rn(v.z, v.z); p3 = __fmul_rn(v.w, v.w);
        float4 w = *(const float4*)&xrow[4];
        p4 = __fmul_rn(w.x, w.x); p5 = __fmul_rn(w.y, w.y);
        p6 = __fmul_rn(w.z, w.z); p7 = __fmul_rn(w.w, w.w);
    }
#pragma unroll
    for (int m = 2; m < 16; m += 2) {
        float4 v = *(const float4*)&xrow[4 * m];        // c = 8m' (mod 8 -> 0..3)
        p0 = __fadd_rn(p0, __fmul_rn(v.x, v.x));
        p1 = __fadd_rn(p1, __fmul_rn(v.y, v.y));
        p2 = __fadd_rn(p2, __fmul_rn(v.z, v.z));
        p3 = __fadd_rn(p3, __fmul_rn(v.w, v.w));
        float4 w = *(const float4*)&xrow[4 * (m + 1)];  // c mod 8 -> 4..7
        p4 = __fadd_rn(p4, __fmul_rn(w.x, w.x));
        p5 = __fadd_rn(p5, __fmul_rn(w.y, w.y));
        p6 = __fadd_rn(p6, __fmul_rn(w.z, w.z));
        p7 = __fadd_rn(p7, __fmul_rn(w.w, w.w));
    }
    const float t1 = __fadd_rn(__fadd_rn(__fadd_rn(p0, p1), __fadd_rn(p2, p3)),
                               __fadd_rn(__fadd_rn(p4, p5), __fadd_rn(p6, p7)));

    const float* __restrict__ t2 = ws_f + 8;

    // ---- k-loop over this thread's half of the codebook ----
    const int k0 = half << 8;
    float best = INFINITY;
    int bestk = k0;

    for (int k = k0; k < k0 + 256; k += 4) {
        const float* e0r = emb + (size_t)(k + 0) * EDIM;  // uniform -> s_load
        const float* e1r = emb + (size_t)(k + 1) * EDIM;
        const float* e2r = emb + (size_t)(k + 2) * EDIM;
        const float* e3r = emb + (size_t)(k + 3) * EDIM;
        float a0 = 0.0f, a1 = 0.0f, a2 = 0.0f, a3 = 0.0f;
#pragma unroll
        for (int m = 0; m < 16; ++m) {
            const float4 xv = *(const float4*)&xrow[4 * m];
            const int c = 4 * m;
            a0 = __fmaf_rn(xv.x, e0r[c + 0], a0);
            a0 = __fmaf_rn(xv.y, e0r[c + 1], a0);
            a0 = __fmaf_rn(xv.z, e0r[c + 2], a0);
            a0 = __fmaf_rn(xv.w, e0r[c + 3], a0);
            a1 = __fmaf_rn(xv.x, e1r[c + 0], a1);
            a1 = __fmaf_rn(xv.y, e1r[c + 1], a1);
            a1 = __fmaf_rn(xv.z, e1r[c + 2], a1);
            a1 = __fmaf_rn(xv.w, e1r[c + 3], a1);
            a2 = __fmaf_rn(xv.x, e2r[c + 0], a2);
            a2 = __fmaf_rn(xv.y, e2r[c + 1], a2);
            a2 = __fmaf_rn(xv.z, e2r[c + 2], a2);
            a2 = __fmaf_rn(xv.w, e2r[c + 3], a2);
            a3 = __fmaf_rn(xv.x, e3r[c + 0], a3);
            a3 = __fmaf_rn(xv.y, e3r[c + 1], a3);
            a3 = __fmaf_rn(xv.z, e3r[c + 2], a3);
            a3 = __fmaf_rn(xv.w, e3r[c + 3], a3);
        }
        // d = fl(fl(t1 + t2) - fl(2*p)); strict < keeps lowest index on ties
        float d0 = __fsub_rn(__fadd_rn(t1, t2[k + 0]), __fmul_rn(2.0f, a0));
        float d1 = __fsub_rn(__fadd_rn(t1, t2[k + 1]), __fmul_rn(2.0f, a1));
        float d2 = __fsub_rn(__fadd_rn(t1, t2[k + 2]), __fmul_rn(2.0f, a2));
        float d3 = __fsub_rn(__fadd_rn(t1, t2[k + 3]), __fmul_rn(2.0f, a3));
        if (d0 < best) { best = d0; bestk = k + 0; }
        if (d1 < best) { best = d1; bestk = k + 1; }
        if (d2 < best) { best = d2; bestk = k + 2; }
        if (d3 < best) { best = d3; bestk = k + 3; }
    }

    // ---- combine the two k-halves (tie -> half 0 = lower k, numpy argmin) ----
    cb[tid] = best;
    ck[tid] = bestk;
    __syncthreads();
    const float bA = cb[rl];
    const float bB = cb[256 + rl];
    const int   kA = ck[rl];
    const int   kB = ck[256 + rl];
    const int   kk = (bB < bA) ? kB : kA;

    // ---- epilogue: each half writes its 32 channels of qst + loss partial ----
    const float* eb = emb + (size_t)kk * EDIM;
    float s = 0.0f;
#pragma unroll
    for (int j = 0; j < 8; ++j) {
        const int c0 = half * 32 + j * 4;
        const float4 xv = *(const float4*)&xrow[c0];
        float q0 = eb[c0 + 0], q1 = eb[c0 + 1], q2 = eb[c0 + 2], q3 = eb[c0 + 3];
        float f0 = __fsub_rn(q0, xv.x);
        float f1 = __fsub_rn(q1, xv.y);
        float f2 = __fsub_rn(q2, xv.z);
        float f3 = __fsub_rn(q3, xv.w);
        out[(size_t)(b * EDIM + c0 + 0) * HW + hw] = __fadd_rn(xv.x, f0);
        out[(size_t)(b * EDIM + c0 + 1) * HW + hw] = __fadd_rn(xv.y, f1);
        out[(size_t)(b * EDIM + c0 + 2) * HW + hw] = __fadd_rn(xv.z, f2);
        out[(size_t)(b * EDIM + c0 + 3) * HW + hw] = __fadd_rn(xv.w, f3);
        s = __fmaf_rn(f0, f0, s);
        s = __fmaf_rn(f1, f1, s);
        s = __fmaf_rn(f2, f2, s);
        s = __fmaf_rn(f3, f3, s);
    }

    if (half == 0) out[(size_t)NQ + 2 + r] = (float)kk;  // idx as fp32

    // wave-level reduction of loss partial, one atomic per wave
#pragma unroll
    for (int off = 32; off > 0; off >>= 1) s += __shfl_down(s, off);
    if ((threadIdx.x & 63) == 0) atomicAdd(ws_f, s);
}

__global__ void vq_final(const float* __restrict__ ws_f, float* __restrict__ out) {
    float m = ws_f[0] * (1.0f / (float)NQ);   // 2^-23, exact scaling
    out[NQ + 0] = m;
    out[NQ + 1] = m;
}

extern "C" void kernel_launch(void* const* d_in, const int* in_sizes, int n_in,
                              void* d_out, int out_size, void* d_ws, size_t ws_size,
                              hipStream_t stream) {
    const float* z = (const float*)d_in[0];     // [32, 64, 64, 64] fp32
    const float* emb = (const float*)d_in[1];   // [512, 64] fp32
    float* out = (float*)d_out;
    float* ws_f = (float*)d_ws;

    hipLaunchKernelGGL(vq_prep, dim3(1), dim3(512), 0, stream, emb, ws_f);
    hipLaunchKernelGGL(vq_main, dim3(NROWS / 256), dim3(512), 0, stream, z, emb, out, ws_f);
    hipLaunchKernelGGL(vq_final, dim3(1), dim3(1), 0, stream, ws_f, out);
}